// Round 15
// baseline (93.061 us; speedup 1.0000x reference)
//
#include <hip/hip_runtime.h>
#include <hip/hip_bf16.h>

#define NN 4096
#define FF 512
#define KK 8
#define DD 64

typedef __attribute__((ext_vector_type(8))) short bf16x8;
typedef __attribute__((ext_vector_type(4))) float f32x4;

// Native packed fp32->bf16 (RNE), 1 instr per 2 elements.  [gfx950]
static __device__ __forceinline__ unsigned int cvt_pk_bf16(float lo, float hi) {
    unsigned int r;
    asm("v_cvt_pk_bf16_f32 %0, %1, %2" : "=v"(r) : "v"(lo), "v"(hi));
    return r;
}

// ---------------------------------------------------------------------------
// K0 (fused cvt): role by blockIdx.x
//   [0, 1024)    : H fp32 -> bf16 (packed cvt)
//   [1024, 1088) : W[k][f][d] -> WT[k][d][f] bf16 via LDS transpose
// ---------------------------------------------------------------------------
__global__ __launch_bounds__(256) void prep_cvt_k(const float* __restrict__ H,
                                                  const float* __restrict__ W,
                                                  uint4* __restrict__ Hb4,
                                                  ushort* __restrict__ WT) {
    __shared__ float lds[64][65];
    int bid = blockIdx.x;
    int t = threadIdx.x;
    if (bid < 1024) {
        int i = bid * 256 + t;
        float4 a = ((const float4*)H)[i * 2];
        float4 b = ((const float4*)H)[i * 2 + 1];
        uint4 v;
        v.x = cvt_pk_bf16(a.x, a.y);
        v.y = cvt_pk_bf16(a.z, a.w);
        v.z = cvt_pk_bf16(b.x, b.y);
        v.w = cvt_pk_bf16(b.z, b.w);
        Hb4[i] = v;
    } else {
        int k = (bid - 1024) >> 3, f0 = ((bid - 1024) & 7) * 64;
        const float* src = W + ((size_t)k * FF + f0) * DD;
#pragma unroll
        for (int i = 0; i < 4; ++i) {
            int idx4 = t + i * 256;
            int f = idx4 >> 4, d4 = (idx4 & 15) * 4;
            float4 v = *(const float4*)(src + (size_t)f * DD + d4);
            lds[f][d4 + 0] = v.x; lds[f][d4 + 1] = v.y;
            lds[f][d4 + 2] = v.z; lds[f][d4 + 3] = v.w;
        }
        __syncthreads();
        int d = t >> 2, fs = (t & 3) * 16;
        ushort* dst = WT + ((size_t)k * DD + d) * FF + f0 + fs;
        uint4 v0, v1;
        v0.x = cvt_pk_bf16(lds[fs + 0][d], lds[fs + 1][d]);
        v0.y = cvt_pk_bf16(lds[fs + 2][d], lds[fs + 3][d]);
        v0.z = cvt_pk_bf16(lds[fs + 4][d], lds[fs + 5][d]);
        v0.w = cvt_pk_bf16(lds[fs + 6][d], lds[fs + 7][d]);
        v1.x = cvt_pk_bf16(lds[fs + 8][d], lds[fs + 9][d]);
        v1.y = cvt_pk_bf16(lds[fs + 10][d], lds[fs + 11][d]);
        v1.z = cvt_pk_bf16(lds[fs + 12][d], lds[fs + 13][d]);
        v1.w = cvt_pk_bf16(lds[fs + 14][d], lds[fs + 15][d]);
        *(uint4*)dst = v0;
        *(uint4*)(dst + 8) = v1;
    }
}

// ---------------------------------------------------------------------------
// K1 (fused pack + GEMM): PACK FIRST ([0,1024)) so the 67 MB HBM long pole
// starts streaming at t=0; GEMM blocks ([1024,1536)) fill in behind.
//   pack: nibble + shfl-OR butterfly (verbatim R13, bit-identical Abits)
//   gemm: verbatim math + j-parity 1-ahead register prefetch of A/B frags
//         (the R10-proven fix for serial load->MFMA chains; clamped last
//         prefetch re-reads iter 15, value unused)
// ---------------------------------------------------------------------------
__global__ __launch_bounds__(256) void pack_gemm_k(const float* __restrict__ A,
                                                   const ushort* __restrict__ Hb,
                                                   const ushort* __restrict__ WT,
                                                   const float* __restrict__ ak1,
                                                   const float* __restrict__ ak2,
                                                   float* __restrict__ r1,
                                                   float* __restrict__ E2,
                                                   float* __restrict__ e2p,
                                                   ushort* __restrict__ HWT2,
                                                   unsigned int* __restrict__ Abits) {
    int bid = blockIdx.x;
    int t = threadIdx.x;
    if (bid < 1024) {
        int prow = bid * 4 + (t >> 6);                 // A row 0..4095
        int lane = t & 63;
        unsigned long long* Ab64 = (unsigned long long*)Abits;
        const float4* Ap = (const float4*)(A + (size_t)prow * NN) + lane;
        int shl = 4 * (lane & 7);
        bool hiSel = (lane & 8) != 0;
#pragma unroll
        for (int c = 0; c < 16; ++c) {
            float4 v = Ap[c * 64];
            unsigned int nib = (v.x != 0.f ? 1u : 0u)
                             | (v.y != 0.f ? 2u : 0u)
                             | (v.z != 0.f ? 4u : 0u)
                             | (v.w != 0.f ? 8u : 0u);
            unsigned int sh = nib << shl;
            unsigned int lo = hiSel ? 0u : sh;
            unsigned int hi = hiSel ? sh : 0u;
#pragma unroll
            for (int off = 1; off <= 8; off <<= 1) {
                lo |= __shfl_xor(lo, off);
                hi |= __shfl_xor(hi, off);
            }
            if ((lane & 15) == 0) {
                unsigned long long word = ((unsigned long long)hi << 32) | (unsigned long long)lo;
                Ab64[(size_t)prow * 64 + c * 4 + (lane >> 4)] = word;
            }
        }
        return;
    }
    int g = bid - 1024;
    int k = g & 7;
    int wrow = (g >> 3) * 64 + (t >> 6) * 16;
    int l = t & 63;
    int lr = l & 15, lg = l >> 4;

    f32x4 acc[4];
#pragma unroll
    for (int f = 0; f < 4; ++f) acc[f] = (f32x4){0.f, 0.f, 0.f, 0.f};

    const ushort* ha = Hb + (size_t)(wrow + lr) * FF + lg * 8;
    const ushort* wa = WT + (size_t)(k * DD + lr) * FF + lg * 8;

    // ---- j-parity 1-ahead prefetch (slots A/B) ----
    bf16x8 aA, aB, bA[4], bB[4];
    aA = *(const bf16x8*)(ha);
#pragma unroll
    for (int f = 0; f < 4; ++f) bA[f] = *(const bf16x8*)(wa + (size_t)f * 16 * FF);

#pragma unroll
    for (int t2 = 0; t2 < 8; ++t2) {
        // j=0: prefetch iter 2*t2+1 -> slot B; MFMA on slot A
        int f1 = (2 * t2 + 1) * 32;
        aB = *(const bf16x8*)(ha + f1);
#pragma unroll
        for (int f = 0; f < 4; ++f) bB[f] = *(const bf16x8*)(wa + (size_t)f * 16 * FF + f1);
#pragma unroll
        for (int f = 0; f < 4; ++f)
            acc[f] = __builtin_amdgcn_mfma_f32_16x16x32_bf16(aA, bA[f], acc[f], 0, 0, 0);
        // j=1: prefetch iter 2*t2+2 (clamped: last re-reads iter 15, unused) -> slot A
        int f2 = (2 * t2 + 2) * 32;
        f2 -= (f2 >> 9) << 5;                  // 512 -> 480
        aA = *(const bf16x8*)(ha + f2);
#pragma unroll
        for (int f = 0; f < 4; ++f) bA[f] = *(const bf16x8*)(wa + (size_t)f * 16 * FF + f2);
#pragma unroll
        for (int f = 0; f < 4; ++f)
            acc[f] = __builtin_amdgcn_mfma_f32_16x16x32_bf16(aB, bB[f], acc[f], 0, 0, 0);
    }

    float p1[4] = {0.f, 0.f, 0.f, 0.f}, p2[4] = {0.f, 0.f, 0.f, 0.f};
#pragma unroll
    for (int f = 0; f < 4; ++f) {
        float a1 = ak1[k * DD + f * 16 + lr];
        float a2 = ak2[k * DD + f * 16 + lr];
#pragma unroll
        for (int i = 0; i < 4; ++i) {
            p1[i] = fmaf(acc[f][i], a1, p1[i]);
            p2[i] = fmaf(acc[f][i], a2, p2[i]);
        }
    }
#pragma unroll
    for (int off = 1; off < 16; off <<= 1) {
#pragma unroll
        for (int i = 0; i < 4; ++i) {
            p1[i] += __shfl_xor(p1[i], off);
            p2[i] += __shfl_xor(p2[i], off);
        }
    }
    if (lr == 0) {
#pragma unroll
        for (int i = 0; i < 4; ++i) {
            int n = k * NN + wrow + lg * 4 + i;
            r1[n]  = __expf(-0.8f * p1[i]);
            E2[n]  = __expf(p2[i]);
            e2p[n] = __expf(0.2f * p2[i]);
        }
    }
    // m-tiled store: HWT2[(k*512 + n/8)*512 + d*8 + n%8]
    size_t basei = ((size_t)(k * 512 + (wrow >> 3) + (lg >> 1))) * 512
                 + (size_t)lr * 8 + (lg & 1) * 4;
#pragma unroll
    for (int f = 0; f < 4; ++f) {
        uint2 v;
        v.x = cvt_pk_bf16(acc[f][0], acc[f][1]);
        v.y = cvt_pk_bf16(acc[f][2], acc[f][3]);
        *(uint2*)&HWT2[basei + (size_t)f * 128] = v;
    }
}

// ---------------------------------------------------------------------------
// K2: fully fused scores + PV + softmax-divide.  Verbatim R13 kernel.
// Grid: 1024 blocks, k = bid & 7 (XCD-clustered).  Block = 4 waves sharing
// 32 rows; wave w owns m-quarter [w*1024, +1024).  Tables E2/e2p fp32 in 32KB
// LDS, reused as reduce buffer after the loop.  B-frags from m-tiled HWT2
// (one base + const offsets, 4x contiguous 256B segments), 1-ahead register
// double-buffer (j-parity), clamped prefetch.  Score: exp(leaky(s1+s2)-s1)
// = max(E2[m], r1[n]*e2p[m]); mask = sign-extended bit AND on fp32 bits;
// pack via v_cvt_pk_bf16_f32.  Row sums via ones-column MFMA.
// ---------------------------------------------------------------------------
__global__ __launch_bounds__(256) void attn_pv_f(const ushort* __restrict__ HWT2,
                                                 const float* __restrict__ r1v,
                                                 const float* __restrict__ E2v,
                                                 const float* __restrict__ e2pv,
                                                 const unsigned char* __restrict__ Ab8,
                                                 const float* __restrict__ bias,
                                                 float* __restrict__ out) {
    int b = blockIdx.x;
    int k = b & 7;
    int row0 = (b >> 3) * 32;

    int w = threadIdx.x >> 6;                 // wave = m-quarter
    int l = threadIdx.x & 63;
    int lr = l & 15, lg = l >> 4;

    __shared__ float tb[8192];                // E2[4096] | e2p[4096]; reused as reduce buf
    __shared__ float ps[4][32];               // per-wave row sums

    {   // stage tables (coalesced float4)
        const float4* e2s = (const float4*)(E2v + (size_t)k * NN);
        const float4* qps = (const float4*)(e2pv + (size_t)k * NN);
        float4* t4p = (float4*)tb;
#pragma unroll
        for (int n = 0; n < 4; ++n) {
            t4p[threadIdx.x + n * 256]        = e2s[threadIdx.x + n * 256];
            t4p[1024 + threadIdx.x + n * 256] = qps[threadIdx.x + n * 256];
        }
    }
    __syncthreads();

    float r1r0 = r1v[k * NN + row0 + lr];
    float r1r1 = r1v[k * NN + row0 + 16 + lr];
    const uint4* mrow0 = (const uint4*)(Ab8 + (size_t)(row0 + lr) * (NN / 8) + w * 128);
    const uint4* mrow1 = (const uint4*)(Ab8 + (size_t)(row0 + 16 + lr) * (NN / 8) + w * 128);
    const ushort* hwg = HWT2 + ((size_t)(k * 512 + w * 128 + lg)) * 512 + (size_t)lr * 8;
    const float* tE = tb + w * 1024 + lg * 8;
    const float* tQ = tb + 4096 + w * 1024 + lg * 8;

    bf16x8 onesb;
#pragma unroll
    for (int j = 0; j < 8; ++j) onesb[j] = (lr == 0) ? (short)0x3F80 : (short)0;

    f32x4 acc0[4], acc1[4];
#pragma unroll
    for (int f = 0; f < 4; ++f) {
        acc0[f] = (f32x4){0.f, 0.f, 0.f, 0.f};
        acc1[f] = (f32x4){0.f, 0.f, 0.f, 0.f};
    }
    f32x4 accs0 = (f32x4){0.f, 0.f, 0.f, 0.f};
    f32x4 accs1 = (f32x4){0.f, 0.f, 0.f, 0.f};

    bf16x8 bb[2][4];
#pragma unroll
    for (int f = 0; f < 4; ++f) bb[0][f] = *(const bf16x8*)(hwg + f * 128);

    for (int t4 = 0; t4 < 8; ++t4) {          // 8 x 4 = 32 iters of 32 m
        uint4 mu0 = mrow0[t4], mu1 = mrow1[t4];
        unsigned int mw0[4] = {mu0.x, mu0.y, mu0.z, mu0.w};
        unsigned int mw1[4] = {mu1.x, mu1.y, mu1.z, mu1.w};
#pragma unroll
        for (int j = 0; j < 4; ++j) {
            int it = t4 * 4 + j;
            const int cur = j & 1, nxt = cur ^ 1;
            // prefetch next B-frags (clamped: it=31 re-reads it 31, unused)
            int itn = it + 1 - ((it + 1) >> 5);
#pragma unroll
            for (int f = 0; f < 4; ++f)
                bb[nxt][f] = *(const bf16x8*)(hwg + (size_t)itn * 2048 + f * 128);
            const float* ltE = tE + it * 32;
            const float* ltQ = tQ + it * 32;
            float4 ea = *(const float4*)(ltE), eb = *(const float4*)(ltE + 4);
            float4 qa = *(const float4*)(ltQ), qb = *(const float4*)(ltQ + 4);
            float ev[8] = {ea.x, ea.y, ea.z, ea.w, eb.x, eb.y, eb.z, eb.w};
            float qv[8] = {qa.x, qa.y, qa.z, qa.w, qb.x, qb.y, qb.z, qb.w};
            unsigned int mb0 = (mw0[j] >> (lg * 8)) & 0xffu;
            unsigned int mb1 = (mw1[j] >> (lg * 8)) & 0xffu;
            uint4 au0, au1;
            unsigned int* pu0 = &au0.x;
            unsigned int* pu1 = &au1.x;
#pragma unroll
            for (int p = 0; p < 4; ++p) {
                int ja = 2 * p, jb = 2 * p + 1;
                unsigned int m0a = (unsigned int)(((int)(mb0 << (31 - ja))) >> 31);
                unsigned int m0b = (unsigned int)(((int)(mb0 << (31 - jb))) >> 31);
                unsigned int m1a = (unsigned int)(((int)(mb1 << (31 - ja))) >> 31);
                unsigned int m1b = (unsigned int)(((int)(mb1 << (31 - jb))) >> 31);
                float y0a = fmaxf(ev[ja], r1r0 * qv[ja]);
                float y0b = fmaxf(ev[jb], r1r0 * qv[jb]);
                float y1a = fmaxf(ev[ja], r1r1 * qv[ja]);
                float y1b = fmaxf(ev[jb], r1r1 * qv[jb]);
                y0a = __uint_as_float(__float_as_uint(y0a) & m0a);
                y0b = __uint_as_float(__float_as_uint(y0b) & m0b);
                y1a = __uint_as_float(__float_as_uint(y1a) & m1a);
                y1b = __uint_as_float(__float_as_uint(y1b) & m1b);
                pu0[p] = cvt_pk_bf16(y0a, y0b);
                pu1[p] = cvt_pk_bf16(y1a, y1b);
            }
            bf16x8 af0 = __builtin_bit_cast(bf16x8, au0);
            bf16x8 af1 = __builtin_bit_cast(bf16x8, au1);
            __builtin_amdgcn_s_setprio(1);
            accs0 = __builtin_amdgcn_mfma_f32_16x16x32_bf16(af0, onesb, accs0, 0, 0, 0);
            accs1 = __builtin_amdgcn_mfma_f32_16x16x32_bf16(af1, onesb, accs1, 0, 0, 0);
#pragma unroll
            for (int f = 0; f < 4; ++f) {
                acc0[f] = __builtin_amdgcn_mfma_f32_16x16x32_bf16(af0, bb[cur][f], acc0[f], 0, 0, 0);
                acc1[f] = __builtin_amdgcn_mfma_f32_16x16x32_bf16(af1, bb[cur][f], acc1[f], 0, 0, 0);
            }
            __builtin_amdgcn_s_setprio(0);
        }
    }

    // ---- cross-wave reduction through LDS (reuse table region) ----
    __syncthreads();                          // everyone done reading tables
#pragma unroll
    for (int f = 0; f < 4; ++f)
#pragma unroll
        for (int i = 0; i < 4; ++i) {
            tb[w * 2048 + (lg * 4 + i) * 64 + f * 16 + lr]      = acc0[f][i];
            tb[w * 2048 + (16 + lg * 4 + i) * 64 + f * 16 + lr] = acc1[f][i];
        }
    if (lr == 0) {
#pragma unroll
        for (int i = 0; i < 4; ++i) {
            ps[w][lg * 4 + i]      = accs0[i];
            ps[w][16 + lg * 4 + i] = accs1[i];
        }
    }
    __syncthreads();

    const float4* red4 = (const float4*)tb;
#pragma unroll
    for (int j2 = 0; j2 < 2; ++j2) {
        int o4 = threadIdx.x + j2 * 256;      // 512 float4 outputs (32 rows x 64 d)
        int row = o4 >> 4, d4 = (o4 & 15) * 4;
        float4 s0 = red4[o4], s1_ = red4[512 + o4];
        float4 s2_ = red4[1024 + o4], s3 = red4[1536 + o4];
        float rs = ps[0][row] + ps[1][row] + ps[2][row] + ps[3][row];
        float inv = 1.f / rs;
        float4 bi = *(const float4*)(bias + k * DD + d4);
        float4 o;
        o.x = fmaxf(fmaf(s0.x + s1_.x + s2_.x + s3.x, inv, bi.x), 0.f);
        o.y = fmaxf(fmaf(s0.y + s1_.y + s2_.y + s3.y, inv, bi.y), 0.f);
        o.z = fmaxf(fmaf(s0.z + s1_.z + s2_.z + s3.z, inv, bi.z), 0.f);
        o.w = fmaxf(fmaf(s0.w + s1_.w + s2_.w + s3.w, inv, bi.w), 0.f);
        *(float4*)&out[(size_t)(row0 + row) * (KK * DD) + k * DD + d4] = o;
    }
}

// ---------------------------------------------------------------------------
extern "C" void kernel_launch(void* const* d_in, const int* in_sizes, int n_in,
                              void* d_out, int out_size, void* d_ws, size_t ws_size,
                              hipStream_t stream) {
    const float* H   = (const float*)d_in[0];
    const float* A   = (const float*)d_in[1];
    // d_in[2] = idx (arange(N)) -> batch_A == A, unused
    const float* W   = (const float*)d_in[3];
    const float* b   = (const float*)d_in[4];
    const float* ak1 = (const float*)d_in[5];
    const float* ak2 = (const float*)d_in[6];
    float* out = (float*)d_out;

    char* ws = (char*)d_ws;
    size_t off = 0;
    ushort* Hb   = (ushort*)(ws + off); off += (size_t)NN * FF * 2;        // 4 MB
    ushort* HWT2 = (ushort*)(ws + off); off += (size_t)KK * DD * NN * 2;   // 4 MB
    ushort* WT   = (ushort*)(ws + off); off += (size_t)KK * DD * FF * 2;   // 0.5 MB
    unsigned int* Abits = (unsigned int*)(ws + off); off += (size_t)NN * NN / 8; // 2 MB
    float* r1  = (float*)(ws + off); off += (size_t)KK * NN * 4;
    float* E2  = (float*)(ws + off); off += (size_t)KK * NN * 4;
    float* e2p = (float*)(ws + off); off += (size_t)KK * NN * 4;

    prep_cvt_k<<<dim3(1024 + 64), 256, 0, stream>>>(H, W, (uint4*)Hb, WT);
    pack_gemm_k<<<dim3(1024 + 512), 256, 0, stream>>>(A, Hb, WT, ak1, ak2,
                                                      r1, E2, e2p, HWT2, Abits);
    attn_pv_f<<<dim3(KK * (NN / 32)), 256, 0, stream>>>(
        HWT2, r1, E2, e2p, (const unsigned char*)Abits, b, out);
}

// Round 16
// 70.393 us; speedup vs baseline: 1.3220x; 1.3220x over previous
//
#include <hip/hip_runtime.h>
#include <hip/hip_bf16.h>

#define NN 4096
#define FF 512
#define KK 8
#define DD 64

typedef __attribute__((ext_vector_type(8))) short bf16x8;
typedef __attribute__((ext_vector_type(4))) float f32x4;

// Native packed fp32->bf16 (RNE), 1 instr per 2 elements.  [gfx950]
static __device__ __forceinline__ unsigned int cvt_pk_bf16(float lo, float hi) {
    unsigned int r;
    asm("v_cvt_pk_bf16_f32 %0, %1, %2" : "=v"(r) : "v"(lo), "v"(hi));
    return r;
}

// ---------------------------------------------------------------------------
// K0 (fused cvt): role by blockIdx.x
//   [0, 1024)    : H fp32 -> bf16 (packed cvt)
//   [1024, 1088) : W[k][f][d] -> WT[k][d][f] bf16 via LDS transpose
// ---------------------------------------------------------------------------
__global__ __launch_bounds__(256) void prep_cvt_k(const float* __restrict__ H,
                                                  const float* __restrict__ W,
                                                  uint4* __restrict__ Hb4,
                                                  ushort* __restrict__ WT) {
    __shared__ float lds[64][65];
    int bid = blockIdx.x;
    int t = threadIdx.x;
    if (bid < 1024) {
        int i = bid * 256 + t;
        float4 a = ((const float4*)H)[i * 2];
        float4 b = ((const float4*)H)[i * 2 + 1];
        uint4 v;
        v.x = cvt_pk_bf16(a.x, a.y);
        v.y = cvt_pk_bf16(a.z, a.w);
        v.z = cvt_pk_bf16(b.x, b.y);
        v.w = cvt_pk_bf16(b.z, b.w);
        Hb4[i] = v;
    } else {
        int k = (bid - 1024) >> 3, f0 = ((bid - 1024) & 7) * 64;
        const float* src = W + ((size_t)k * FF + f0) * DD;
#pragma unroll
        for (int i = 0; i < 4; ++i) {
            int idx4 = t + i * 256;
            int f = idx4 >> 4, d4 = (idx4 & 15) * 4;
            float4 v = *(const float4*)(src + (size_t)f * DD + d4);
            lds[f][d4 + 0] = v.x; lds[f][d4 + 1] = v.y;
            lds[f][d4 + 2] = v.z; lds[f][d4 + 3] = v.w;
        }
        __syncthreads();
        int d = t >> 2, fs = (t & 3) * 16;
        ushort* dst = WT + ((size_t)k * DD + d) * FF + f0 + fs;
        uint4 v0, v1;
        v0.x = cvt_pk_bf16(lds[fs + 0][d], lds[fs + 1][d]);
        v0.y = cvt_pk_bf16(lds[fs + 2][d], lds[fs + 3][d]);
        v0.z = cvt_pk_bf16(lds[fs + 4][d], lds[fs + 5][d]);
        v0.w = cvt_pk_bf16(lds[fs + 6][d], lds[fs + 7][d]);
        v1.x = cvt_pk_bf16(lds[fs + 8][d], lds[fs + 9][d]);
        v1.y = cvt_pk_bf16(lds[fs + 10][d], lds[fs + 11][d]);
        v1.z = cvt_pk_bf16(lds[fs + 12][d], lds[fs + 13][d]);
        v1.w = cvt_pk_bf16(lds[fs + 14][d], lds[fs + 15][d]);
        *(uint4*)dst = v0;
        *(uint4*)(dst + 8) = v1;
    }
}

// ---------------------------------------------------------------------------
// K1 (fused GEMM + mask pack), 512 threads (8 waves).  R13 ordering (gemm
// first); R15's prefetch REVERTED (it flooded the memory queues: 55 us with
// all pipes idle).  ONE change vs R13: in-block f-split for the GEMM role.
//   [0, 512)    : gemm, 8 waves = 4 row-groups (rh) x 2 f-halves (fh).
//                 Each wave: 8 K-iters over f in [fh*256, fh*256+256).
//                 fh=1 dumps acc to 16KB LDS; barrier; fh=0 adds and runs
//                 the verbatim epilogue (s1/s2, tables, m-tiled store).
//                 Halves the serial K-chain, doubles gemm TLP.
//   [512, 1024) : pack A -> bitmask, nibble + shfl-OR butterfly (verbatim,
//                 bit-identical Abits), 8 rows per block.
// ---------------------------------------------------------------------------
__global__ __launch_bounds__(512) void gemm_pack_k(const ushort* __restrict__ Hb,
                                                   const ushort* __restrict__ WT,
                                                   const float* __restrict__ ak1,
                                                   const float* __restrict__ ak2,
                                                   const float* __restrict__ A,
                                                   float* __restrict__ r1,
                                                   float* __restrict__ E2,
                                                   float* __restrict__ e2p,
                                                   ushort* __restrict__ HWT2,
                                                   unsigned int* __restrict__ Abits) {
    __shared__ float red[4][16][64];                   // 16 KB f-half reduce
    int bid = blockIdx.x;
    int t = threadIdx.x;
    int wid = t >> 6;
    int l = t & 63;
    if (bid >= 512) {
        int prow = (bid - 512) * 8 + wid;              // A row 0..4095
        unsigned long long* Ab64 = (unsigned long long*)Abits;
        const float4* Ap = (const float4*)(A + (size_t)prow * NN) + l;
        int shl = 4 * (l & 7);
        bool hiSel = (l & 8) != 0;
#pragma unroll
        for (int c = 0; c < 16; ++c) {
            float4 v = Ap[c * 64];
            unsigned int nib = (v.x != 0.f ? 1u : 0u)
                             | (v.y != 0.f ? 2u : 0u)
                             | (v.z != 0.f ? 4u : 0u)
                             | (v.w != 0.f ? 8u : 0u);
            unsigned int sh = nib << shl;
            unsigned int lo = hiSel ? 0u : sh;
            unsigned int hi = hiSel ? sh : 0u;
#pragma unroll
            for (int off = 1; off <= 8; off <<= 1) {
                lo |= __shfl_xor(lo, off);
                hi |= __shfl_xor(hi, off);
            }
            if ((l & 15) == 0) {
                unsigned long long word = ((unsigned long long)hi << 32) | (unsigned long long)lo;
                Ab64[(size_t)prow * 64 + c * 4 + (l >> 4)] = word;
            }
        }
        return;
    }
    int k = bid & 7;
    int rh = wid & 3, fh = wid >> 2;
    int wrow = (bid >> 3) * 64 + rh * 16;
    int lr = l & 15, lg = l >> 4;

    f32x4 acc[4];
#pragma unroll
    for (int f = 0; f < 4; ++f) acc[f] = (f32x4){0.f, 0.f, 0.f, 0.f};

    const ushort* ha = Hb + (size_t)(wrow + lr) * FF + fh * 256 + lg * 8;
    const ushort* wa = WT + (size_t)(k * DD + lr) * FF + fh * 256 + lg * 8;
#pragma unroll 4
    for (int f0 = 0; f0 < 256; f0 += 32) {
        bf16x8 a = *(const bf16x8*)(ha + f0);
#pragma unroll
        for (int f = 0; f < 4; ++f) {
            bf16x8 b = *(const bf16x8*)(wa + (size_t)f * 16 * FF + f0);
            acc[f] = __builtin_amdgcn_mfma_f32_16x16x32_bf16(a, b, acc[f], 0, 0, 0);
        }
    }

    // ---- combine f-halves through LDS ----
    if (fh == 1) {
#pragma unroll
        for (int f = 0; f < 4; ++f)
#pragma unroll
            for (int i = 0; i < 4; ++i)
                red[rh][lg * 4 + i][f * 16 + lr] = acc[f][i];
    }
    __syncthreads();
    if (fh == 1) return;
#pragma unroll
    for (int f = 0; f < 4; ++f)
#pragma unroll
        for (int i = 0; i < 4; ++i)
            acc[f][i] += red[rh][lg * 4 + i][f * 16 + lr];

    float p1[4] = {0.f, 0.f, 0.f, 0.f}, p2[4] = {0.f, 0.f, 0.f, 0.f};
#pragma unroll
    for (int f = 0; f < 4; ++f) {
        float a1 = ak1[k * DD + f * 16 + lr];
        float a2 = ak2[k * DD + f * 16 + lr];
#pragma unroll
        for (int i = 0; i < 4; ++i) {
            p1[i] = fmaf(acc[f][i], a1, p1[i]);
            p2[i] = fmaf(acc[f][i], a2, p2[i]);
        }
    }
#pragma unroll
    for (int off = 1; off < 16; off <<= 1) {
#pragma unroll
        for (int i = 0; i < 4; ++i) {
            p1[i] += __shfl_xor(p1[i], off);
            p2[i] += __shfl_xor(p2[i], off);
        }
    }
    if (lr == 0) {
#pragma unroll
        for (int i = 0; i < 4; ++i) {
            int n = k * NN + wrow + lg * 4 + i;
            r1[n]  = __expf(-0.8f * p1[i]);
            E2[n]  = __expf(p2[i]);
            e2p[n] = __expf(0.2f * p2[i]);
        }
    }
    // m-tiled store: HWT2[(k*512 + n/8)*512 + d*8 + n%8]
    size_t basei = ((size_t)(k * 512 + (wrow >> 3) + (lg >> 1))) * 512
                 + (size_t)lr * 8 + (lg & 1) * 4;
#pragma unroll
    for (int f = 0; f < 4; ++f) {
        uint2 v;
        v.x = cvt_pk_bf16(acc[f][0], acc[f][1]);
        v.y = cvt_pk_bf16(acc[f][2], acc[f][3]);
        *(uint2*)&HWT2[basei + (size_t)f * 128] = v;
    }
}

// ---------------------------------------------------------------------------
// K2: fully fused scores + PV + softmax-divide.  Verbatim R13 kernel.
// Grid: 1024 blocks, k = bid & 7 (XCD-clustered).  Block = 4 waves sharing
// 32 rows; wave w owns m-quarter [w*1024, +1024).  Tables E2/e2p fp32 in 32KB
// LDS, reused as reduce buffer after the loop.  B-frags from m-tiled HWT2
// (one base + const offsets, 4x contiguous 256B segments), 1-ahead register
// double-buffer (j-parity), clamped prefetch.  Score: exp(leaky(s1+s2)-s1)
// = max(E2[m], r1[n]*e2p[m]); mask = sign-extended bit AND on fp32 bits;
// pack via v_cvt_pk_bf16_f32.  Row sums via ones-column MFMA.
// ---------------------------------------------------------------------------
__global__ __launch_bounds__(256) void attn_pv_f(const ushort* __restrict__ HWT2,
                                                 const float* __restrict__ r1v,
                                                 const float* __restrict__ E2v,
                                                 const float* __restrict__ e2pv,
                                                 const unsigned char* __restrict__ Ab8,
                                                 const float* __restrict__ bias,
                                                 float* __restrict__ out) {
    int b = blockIdx.x;
    int k = b & 7;
    int row0 = (b >> 3) * 32;

    int w = threadIdx.x >> 6;                 // wave = m-quarter
    int l = threadIdx.x & 63;
    int lr = l & 15, lg = l >> 4;

    __shared__ float tb[8192];                // E2[4096] | e2p[4096]; reused as reduce buf
    __shared__ float ps[4][32];               // per-wave row sums

    {   // stage tables (coalesced float4)
        const float4* e2s = (const float4*)(E2v + (size_t)k * NN);
        const float4* qps = (const float4*)(e2pv + (size_t)k * NN);
        float4* t4p = (float4*)tb;
#pragma unroll
        for (int n = 0; n < 4; ++n) {
            t4p[threadIdx.x + n * 256]        = e2s[threadIdx.x + n * 256];
            t4p[1024 + threadIdx.x + n * 256] = qps[threadIdx.x + n * 256];
        }
    }
    __syncthreads();

    float r1r0 = r1v[k * NN + row0 + lr];
    float r1r1 = r1v[k * NN + row0 + 16 + lr];
    const uint4* mrow0 = (const uint4*)(Ab8 + (size_t)(row0 + lr) * (NN / 8) + w * 128);
    const uint4* mrow1 = (const uint4*)(Ab8 + (size_t)(row0 + 16 + lr) * (NN / 8) + w * 128);
    const ushort* hwg = HWT2 + ((size_t)(k * 512 + w * 128 + lg)) * 512 + (size_t)lr * 8;
    const float* tE = tb + w * 1024 + lg * 8;
    const float* tQ = tb + 4096 + w * 1024 + lg * 8;

    bf16x8 onesb;
#pragma unroll
    for (int j = 0; j < 8; ++j) onesb[j] = (lr == 0) ? (short)0x3F80 : (short)0;

    f32x4 acc0[4], acc1[4];
#pragma unroll
    for (int f = 0; f < 4; ++f) {
        acc0[f] = (f32x4){0.f, 0.f, 0.f, 0.f};
        acc1[f] = (f32x4){0.f, 0.f, 0.f, 0.f};
    }
    f32x4 accs0 = (f32x4){0.f, 0.f, 0.f, 0.f};
    f32x4 accs1 = (f32x4){0.f, 0.f, 0.f, 0.f};

    bf16x8 bb[2][4];
#pragma unroll
    for (int f = 0; f < 4; ++f) bb[0][f] = *(const bf16x8*)(hwg + f * 128);

    for (int t4 = 0; t4 < 8; ++t4) {          // 8 x 4 = 32 iters of 32 m
        uint4 mu0 = mrow0[t4], mu1 = mrow1[t4];
        unsigned int mw0[4] = {mu0.x, mu0.y, mu0.z, mu0.w};
        unsigned int mw1[4] = {mu1.x, mu1.y, mu1.z, mu1.w};
#pragma unroll
        for (int j = 0; j < 4; ++j) {
            int it = t4 * 4 + j;
            const int cur = j & 1, nxt = cur ^ 1;
            // prefetch next B-frags (clamped: it=31 re-reads it 31, unused)
            int itn = it + 1 - ((it + 1) >> 5);
#pragma unroll
            for (int f = 0; f < 4; ++f)
                bb[nxt][f] = *(const bf16x8*)(hwg + (size_t)itn * 2048 + f * 128);
            const float* ltE = tE + it * 32;
            const float* ltQ = tQ + it * 32;
            float4 ea = *(const float4*)(ltE), eb = *(const float4*)(ltE + 4);
            float4 qa = *(const float4*)(ltQ), qb = *(const float4*)(ltQ + 4);
            float ev[8] = {ea.x, ea.y, ea.z, ea.w, eb.x, eb.y, eb.z, eb.w};
            float qv[8] = {qa.x, qa.y, qa.z, qa.w, qb.x, qb.y, qb.z, qb.w};
            unsigned int mb0 = (mw0[j] >> (lg * 8)) & 0xffu;
            unsigned int mb1 = (mw1[j] >> (lg * 8)) & 0xffu;
            uint4 au0, au1;
            unsigned int* pu0 = &au0.x;
            unsigned int* pu1 = &au1.x;
#pragma unroll
            for (int p = 0; p < 4; ++p) {
                int ja = 2 * p, jb = 2 * p + 1;
                unsigned int m0a = (unsigned int)(((int)(mb0 << (31 - ja))) >> 31);
                unsigned int m0b = (unsigned int)(((int)(mb0 << (31 - jb))) >> 31);
                unsigned int m1a = (unsigned int)(((int)(mb1 << (31 - ja))) >> 31);
                unsigned int m1b = (unsigned int)(((int)(mb1 << (31 - jb))) >> 31);
                float y0a = fmaxf(ev[ja], r1r0 * qv[ja]);
                float y0b = fmaxf(ev[jb], r1r0 * qv[jb]);
                float y1a = fmaxf(ev[ja], r1r1 * qv[ja]);
                float y1b = fmaxf(ev[jb], r1r1 * qv[jb]);
                y0a = __uint_as_float(__float_as_uint(y0a) & m0a);
                y0b = __uint_as_float(__float_as_uint(y0b) & m0b);
                y1a = __uint_as_float(__float_as_uint(y1a) & m1a);
                y1b = __uint_as_float(__float_as_uint(y1b) & m1b);
                pu0[p] = cvt_pk_bf16(y0a, y0b);
                pu1[p] = cvt_pk_bf16(y1a, y1b);
            }
            bf16x8 af0 = __builtin_bit_cast(bf16x8, au0);
            bf16x8 af1 = __builtin_bit_cast(bf16x8, au1);
            __builtin_amdgcn_s_setprio(1);
            accs0 = __builtin_amdgcn_mfma_f32_16x16x32_bf16(af0, onesb, accs0, 0, 0, 0);
            accs1 = __builtin_amdgcn_mfma_f32_16x16x32_bf16(af1, onesb, accs1, 0, 0, 0);
#pragma unroll
            for (int f = 0; f < 4; ++f) {
                acc0[f] = __builtin_amdgcn_mfma_f32_16x16x32_bf16(af0, bb[cur][f], acc0[f], 0, 0, 0);
                acc1[f] = __builtin_amdgcn_mfma_f32_16x16x32_bf16(af1, bb[cur][f], acc1[f], 0, 0, 0);
            }
            __builtin_amdgcn_s_setprio(0);
        }
    }

    // ---- cross-wave reduction through LDS (reuse table region) ----
    __syncthreads();                          // everyone done reading tables
#pragma unroll
    for (int f = 0; f < 4; ++f)
#pragma unroll
        for (int i = 0; i < 4; ++i) {
            tb[w * 2048 + (lg * 4 + i) * 64 + f * 16 + lr]      = acc0[f][i];
            tb[w * 2048 + (16 + lg * 4 + i) * 64 + f * 16 + lr] = acc1[f][i];
        }
    if (lr == 0) {
#pragma unroll
        for (int i = 0; i < 4; ++i) {
            ps[w][lg * 4 + i]      = accs0[i];
            ps[w][16 + lg * 4 + i] = accs1[i];
        }
    }
    __syncthreads();

    const float4* red4 = (const float4*)tb;
#pragma unroll
    for (int j2 = 0; j2 < 2; ++j2) {
        int o4 = threadIdx.x + j2 * 256;      // 512 float4 outputs (32 rows x 64 d)
        int row = o4 >> 4, d4 = (o4 & 15) * 4;
        float4 s0 = red4[o4], s1_ = red4[512 + o4];
        float4 s2_ = red4[1024 + o4], s3 = red4[1536 + o4];
        float rs = ps[0][row] + ps[1][row] + ps[2][row] + ps[3][row];
        float inv = 1.f / rs;
        float4 bi = *(const float4*)(bias + k * DD + d4);
        float4 o;
        o.x = fmaxf(fmaf(s0.x + s1_.x + s2_.x + s3.x, inv, bi.x), 0.f);
        o.y = fmaxf(fmaf(s0.y + s1_.y + s2_.y + s3.y, inv, bi.y), 0.f);
        o.z = fmaxf(fmaf(s0.z + s1_.z + s2_.z + s3.z, inv, bi.z), 0.f);
        o.w = fmaxf(fmaf(s0.w + s1_.w + s2_.w + s3.w, inv, bi.w), 0.f);
        *(float4*)&out[(size_t)(row0 + row) * (KK * DD) + k * DD + d4] = o;
    }
}

// ---------------------------------------------------------------------------
extern "C" void kernel_launch(void* const* d_in, const int* in_sizes, int n_in,
                              void* d_out, int out_size, void* d_ws, size_t ws_size,
                              hipStream_t stream) {
    const float* H   = (const float*)d_in[0];
    const float* A   = (const float*)d_in[1];
    // d_in[2] = idx (arange(N)) -> batch_A == A, unused
    const float* W   = (const float*)d_in[3];
    const float* b   = (const float*)d_in[4];
    const float* ak1 = (const float*)d_in[5];
    const float* ak2 = (const float*)d_in[6];
    float* out = (float*)d_out;

    char* ws = (char*)d_ws;
    size_t off = 0;
    ushort* Hb   = (ushort*)(ws + off); off += (size_t)NN * FF * 2;        // 4 MB
    ushort* HWT2 = (ushort*)(ws + off); off += (size_t)KK * DD * NN * 2;   // 4 MB
    ushort* WT   = (ushort*)(ws + off); off += (size_t)KK * DD * FF * 2;   // 0.5 MB
    unsigned int* Abits = (unsigned int*)(ws + off); off += (size_t)NN * NN / 8; // 2 MB
    float* r1  = (float*)(ws + off); off += (size_t)KK * NN * 4;
    float* E2  = (float*)(ws + off); off += (size_t)KK * NN * 4;
    float* e2p = (float*)(ws + off); off += (size_t)KK * NN * 4;

    prep_cvt_k<<<dim3(1024 + 64), 256, 0, stream>>>(H, W, (uint4*)Hb, WT);
    gemm_pack_k<<<dim3(512 + 512), 512, 0, stream>>>(Hb, WT, ak1, ak2, A,
                                                     r1, E2, e2p, HWT2, Abits);
    attn_pv_f<<<dim3(KK * (NN / 32)), 256, 0, stream>>>(
        HWT2, r1, E2, e2p, (const unsigned char*)Abits, b, out);
}